// Round 4
// baseline (122.544 us; speedup 1.0000x reference)
//
#include <hip/hip_runtime.h>
#include <hip/hip_bf16.h>
#include <float.h>

// FactoredQuantizer: B=8192, M=16, N=256, C=64
// inputs  [B, M, C] fp32;  codebook [M, N, C] fp32
// out = codes [B, M, C] fp32 ++ idx [B, M] (as fp32 values)
//
// Round 13: occupancy fix. Rounds 10/11 proved extra ILP spills; round 12
// proved the A-convert VALU wasn't the bottleneck. Counters say latency-bound
// at 2 waves/SIMD (acc 64 AGPR + 68 arch = 132 of the 512-reg SIMD file).
// This round halves the per-wave tile: wave = 16 rows x 128 codes, so
// acc 32 + afr 24 + bfr 16 + addressing ~= 92 regs -> 5 waves/SIMD.
// Block = 4 waves = 32 rows x 256 codes (X still read exactly once; argmin
// block-local); grid 256x16 = 4096 blocks. Per-acc MFMA accumulation order
// is unchanged -> bit-identical distances. Hot loop still pure global
// dwordx4 + MFMA, zero LDS ops, zero barriers.

#define BQ 8192
#define MQ 16
#define NQ 256
#define CQ 64

typedef short  shortx8 __attribute__((ext_vector_type(8)));
typedef float  f32x4   __attribute__((ext_vector_type(4)));

#define HI_MASK 0xffff0000u

// Truncation 3-split of two floats a,b packed into three dwords
// (low short = a's bf16, high short = b's bf16). Exact: a0+a1+a2 == a.
__device__ __forceinline__ void split3_pair(float a, float b,
                                            uint& q0, uint& q1, uint& q2) {
    const uint ba = __builtin_bit_cast(uint, a);
    const uint bb = __builtin_bit_cast(uint, b);
    q0 = (ba >> 16) | (bb & HI_MASK);
    const float r1a = a - __builtin_bit_cast(float, ba & HI_MASK);
    const float r1b = b - __builtin_bit_cast(float, bb & HI_MASK);
    const uint c1a = __builtin_bit_cast(uint, r1a);
    const uint c1b = __builtin_bit_cast(uint, r1b);
    q1 = (c1a >> 16) | (c1b & HI_MASK);
    const float r2a = r1a - __builtin_bit_cast(float, c1a & HI_MASK);
    const float r2b = r1b - __builtin_bit_cast(float, c1b & HI_MASK);
    q2 = (__builtin_bit_cast(uint, r2a) >> 16) |
         (__builtin_bit_cast(uint, r2b) & HI_MASK);
}

// ---------------------------------------------------------------------------
// Prep: c2[m][n] = sum_k c^2 (fp32, wave-reduced over 8 k-chunk lanes) and
// codebook bf16x3 splits in MFMA B-fragment order:
//   cb3f[frag][lane][u], frag = ((m*3+j)*2+h)*16 + nt, lane = quad*16 + col,
//   holding codebook[m][nt*16+col][h*32+quad*8+u] split j.
// Thread t = (e, kc): e = m*256+n, kc = k-chunk (8 per row).
// ---------------------------------------------------------------------------
__global__ __launch_bounds__(128) void fq_prep_kernel(
        const float* __restrict__ codebook,
        unsigned short* __restrict__ cb3f,
        float* __restrict__ c2) {
    const int t  = blockIdx.x * 128 + threadIdx.x;   // 32768 threads
    const int kc = t & 7;
    const int e  = t >> 3;          // m*256 + n
    const int m  = e >> 8, n = e & 255;
    const int nt = n >> 4, col = n & 15;
    const int h = kc >> 2, quad = kc & 3;

    const float* src = codebook + (size_t)e * CQ + kc * 8;
    const float4 va = *(const float4*)src;
    const float4 vb = *(const float4*)(src + 4);
    const float el[8] = {va.x, va.y, va.z, va.w, vb.x, vb.y, vb.z, vb.w};

    // c2: partial sums live on 8 consecutive lanes (kc = lane&7)
    float s = 0.0f;
    #pragma unroll
    for (int u = 0; u < 8; ++u) s = fmaf(el[u], el[u], s);
    s += __shfl_xor(s, 1, 64);
    s += __shfl_xor(s, 2, 64);
    s += __shfl_xor(s, 4, 64);
    if (kc == 0) c2[e] = s;

    // 3-way truncation split, packed 2 per dword
    uint p0[4], p1[4], p2[4];
    #pragma unroll
    for (int u = 0; u < 4; ++u)
        split3_pair(el[2 * u], el[2 * u + 1], p0[u], p1[u], p2[u]);

    const int lane_f = quad * 16 + col;
    #pragma unroll
    for (int j = 0; j < 3; ++j) {
        const uint* p = (j == 0) ? p0 : (j == 1) ? p1 : p2;
        const int frag = ((m * 3 + j) * 2 + h) * 16 + nt;
        uint4* dst = (uint4*)(cb3f + ((size_t)frag * 64 + lane_f) * 8);
        *dst = make_uint4(p[0], p[1], p[2], p[3]);
    }
}

// ---------------------------------------------------------------------------
// Main: block = 4 waves over 32 rows x 256 codes; wave (rg=w&1, chh=w>>1)
// owns 16 rows x 128 codes: acc = 8 n-tiles of f32x4 = 32 regs,
// afr = 6 shortx8 = 24, bfr = 8 shortx8 = 16. X staged fp32 in LDS once;
// K-loop: 8 coalesced B-fragment dwordx4 loads per (h,j) then (3-j)*8 MFMAs;
// first batch hoisted above the conversion. Grid 256x16 = 4096 blocks.
// ---------------------------------------------------------------------------
__global__ __launch_bounds__(256, 4) void fq_main_kernel(
        const float* __restrict__ inputs,
        const float* __restrict__ codebook,
        const unsigned short* __restrict__ cb3f,
        const float* __restrict__ c2,
        float* __restrict__ out_codes,
        float* __restrict__ out_idx) {
    const int m    = blockIdx.y;
    const int row0 = blockIdx.x * 32;
    const int w    = threadIdx.x >> 6;
    const int lane = threadIdx.x & 63;
    const int quad = lane >> 4;
    const int col  = lane & 15;
    const int rg   = w & 1;    // row half (16 rows)
    const int chh  = w >> 1;   // code half (128 codes)

    __shared__ float sxf[32][68];    // 8704 B (stride 68: float4-aligned)
    __shared__ float s_c2[NQ];
    __shared__ float s_wb[2][32];
    __shared__ int   s_wi[2][32];
    __shared__ int   s_win[32];

    s_c2[threadIdx.x] = c2[m * NQ + threadIdx.x];

    // ---- stage X fp32: 32 rows x 64 floats, coalesced float4 ----
    #pragma unroll
    for (int i = 0; i < 2; ++i) {
        const int f = threadIdx.x + 256 * i;    // 0..511 float4s
        const int r = f >> 4;
        const int c = (f & 15) * 4;
        const float4 v = *(const float4*)(
            inputs + ((size_t)(row0 + r) * MQ + m) * CQ + c);
        *(float4*)&sxf[r][c] = v;
    }
    __syncthreads();

    // ---- hoist first B batch (h=0, j=0) above the A-conversion ----
    shortx8 bfr[8];
    {
        const int frag0 = (m * 3 * 2) * 16 + chh * 8;
        const unsigned short* bp = cb3f + ((size_t)frag0 * 64 + lane) * 8;
        #pragma unroll
        for (int nt = 0; nt < 8; ++nt)
            bfr[nt] = *(const shortx8*)(bp + (size_t)nt * 64 * 8);
    }

    // ---- A-fragments: 6 (i,h), truncation-split into registers ----
    shortx8 afr[3][2];
    #pragma unroll
    for (int h = 0; h < 2; ++h) {
        const float* xp = &sxf[rg * 16 + col][h * 32 + quad * 8];
        const float4 va = *(const float4*)xp;
        const float4 vb = *(const float4*)(xp + 4);
        const float el[8] = {va.x, va.y, va.z, va.w, vb.x, vb.y, vb.z, vb.w};
        uint q0[4], q1[4], q2[4];
        #pragma unroll
        for (int u = 0; u < 4; ++u)
            split3_pair(el[2 * u], el[2 * u + 1], q0[u], q1[u], q2[u]);
        afr[0][h] = __builtin_bit_cast(shortx8,
            make_uint4(q0[0], q0[1], q0[2], q0[3]));
        afr[1][h] = __builtin_bit_cast(shortx8,
            make_uint4(q1[0], q1[1], q1[2], q1[3]));
        afr[2][h] = __builtin_bit_cast(shortx8,
            make_uint4(q2[0], q2[1], q2[2], q2[3]));
    }

    f32x4 acc[8];
    #pragma unroll
    for (int nt = 0; nt < 8; ++nt)
        acc[nt] = (f32x4){0.f, 0.f, 0.f, 0.f};

    // ---- hot loop: pure global dwordx4 + MFMA ----
    #pragma unroll
    for (int h = 0; h < 2; ++h) {
        #pragma unroll
        for (int j = 0; j < 3; ++j) {
            if (!(h == 0 && j == 0)) {
                const int frag0 = ((m * 3 + j) * 2 + h) * 16 + chh * 8;
                const unsigned short* bp =
                    cb3f + ((size_t)frag0 * 64 + lane) * 8;
                #pragma unroll
                for (int nt = 0; nt < 8; ++nt)
                    bfr[nt] = *(const shortx8*)(bp + (size_t)nt * 64 * 8);
            }
            #pragma unroll
            for (int i = 0; i <= 2 - j; ++i) {
                #pragma unroll
                for (int nt = 0; nt < 8; ++nt)
                    acc[nt] = __builtin_amdgcn_mfma_f32_16x16x32_bf16(
                        afr[i][h], bfr[nt], acc[nt], 0, 0, 0);
            }
        }
    }

    // ---- epilogue: d = c2 - 2*xc; per-row argmin, lowest n on ties ----
    float c2r[8];
    #pragma unroll
    for (int nt = 0; nt < 8; ++nt)
        c2r[nt] = s_c2[chh * 128 + nt * 16 + col];

    #pragma unroll
    for (int reg = 0; reg < 4; ++reg) {
        float bd = FLT_MAX; int bi = 0;
        #pragma unroll
        for (int nt = 0; nt < 8; ++nt) {
            const float d = fmaf(-2.0f, acc[nt][reg], c2r[nt]);
            if (d < bd) { bd = d; bi = chh * 128 + nt * 16 + col; }
        }
        #pragma unroll
        for (int mask = 1; mask <= 8; mask <<= 1) {   // over 16 col lanes
            const float od = __shfl_xor(bd, mask, 64);
            const int   oi = __shfl_xor(bi, mask, 64);
            if (od < bd || (od == bd && oi < bi)) { bd = od; bi = oi; }
        }
        if (col == 0) {
            const int r = rg * 16 + quad * 4 + reg;   // row within 32
            s_wb[chh][r] = bd;
            s_wi[chh][r] = bi;
        }
    }
    __syncthreads();

    // cross code-half combine (chh=0 holds lower n: ties keep it)
    if (w == 0 && lane < 32) {
        float bd = s_wb[0][lane]; int bi = s_wi[0][lane];
        const float od = s_wb[1][lane]; const int oi = s_wi[1][lane];
        if (od < bd || (od == bd && oi < bi)) { bd = od; bi = oi; }
        s_win[lane] = bi;
        out_idx[(size_t)(row0 + lane) * MQ + m] = (float)bi;
    }
    __syncthreads();

    // gather codes: wave w writes rows w*8..+7, lane = element (256B st)
    const float* cbm = codebook + (size_t)m * NQ * CQ;
    #pragma unroll 4
    for (int jj = 0; jj < 8; ++jj) {
        const int r  = w * 8 + jj;
        const int bn = s_win[r];
        out_codes[((size_t)(row0 + r) * MQ + m) * CQ + lane] =
            cbm[(size_t)bn * CQ + lane];
    }
}

extern "C" void kernel_launch(void* const* d_in, const int* in_sizes, int n_in,
                              void* d_out, int out_size, void* d_ws, size_t ws_size,
                              hipStream_t stream) {
    const float* inputs   = (const float*)d_in[0];   // [B, M, C]
    const float* codebook = (const float*)d_in[1];   // [M, N, C]
    float* out_codes = (float*)d_out;                        // [B, M, C]
    float* out_idx   = (float*)d_out + (size_t)BQ * MQ * CQ; // [B, M]
    float*          c2   = (float*)d_ws;                     // 16 KB
    unsigned short* cb3f = (unsigned short*)(c2 + MQ * NQ);  // 1.5 MB

    fq_prep_kernel<<<dim3(256), 128, 0, stream>>>(codebook, cb3f, c2);

    fq_main_kernel<<<dim3(BQ / 32, MQ), 256, 0, stream>>>(
        inputs, codebook, cb3f, c2, out_codes, out_idx);
}

// Round 5
// 116.798 us; speedup vs baseline: 1.0492x; 1.0492x over previous
//
#include <hip/hip_runtime.h>
#include <hip/hip_bf16.h>
#include <float.h>

// FactoredQuantizer: B=8192, M=16, N=256, C=64
// inputs  [B, M, C] fp32;  codebook [M, N, C] fp32
// out = codes [B, M, C] fp32 ++ idx [B, M] (as fp32 values)
//
// Round 14: persistent-block fusion. Evidence: occupancy doubling (r13) was
// null, ILP additions spill (r10/r11), convert-VALU cut was null (r12) ->
// the cost is per-block serial overhead replicated 8-16x per CU (stage
// latency, 6 L2 B-batch round-trips per wave-tile, barrier drains, prep
// kernel + launch gap). This round: ONE kernel, grid = 256 blocks = 1/CU
// (16 rowgroups x 16 m), 512 threads; each block transcodes its m's
// codebook slice into LDS ONCE (96 KB, bf16x3 fragment layout), computes
// c2 in-block (prep's exact summation order), then loops 8 tiles of
// 64 rows x 256 codes with X double-buffered via global_load_lds
// (zero-VGPR staging; round-10's verified XOR chunk swizzle). Hot loop:
// ds_read_b128 B-fragments + MFMA. Per-acc MFMA order unchanged ->
// bit-identical distances vs the passing 51 us kernel.

#define BQ 8192
#define MQ 16
#define NQ 256
#define CQ 64
#define RPB 512       // rows per block
#define NTILES 8      // RPB / 64

typedef short  shortx8 __attribute__((ext_vector_type(8)));
typedef float  f32x4   __attribute__((ext_vector_type(4)));

#define HI_MASK 0xffff0000u

// Truncation 3-split of two floats a,b packed into three dwords
// (low short = a's bf16, high short = b's bf16). Exact: a0+a1+a2 == a.
__device__ __forceinline__ void split3_pair(float a, float b,
                                            uint& q0, uint& q1, uint& q2) {
    const uint ba = __builtin_bit_cast(uint, a);
    const uint bb = __builtin_bit_cast(uint, b);
    q0 = (ba >> 16) | (bb & HI_MASK);
    const float r1a = a - __builtin_bit_cast(float, ba & HI_MASK);
    const float r1b = b - __builtin_bit_cast(float, bb & HI_MASK);
    const uint c1a = __builtin_bit_cast(uint, r1a);
    const uint c1b = __builtin_bit_cast(uint, r1b);
    q1 = (c1a >> 16) | (c1b & HI_MASK);
    const float r2a = r1a - __builtin_bit_cast(float, c1a & HI_MASK);
    const float r2b = r1b - __builtin_bit_cast(float, c1b & HI_MASK);
    q2 = (__builtin_bit_cast(uint, r2a) >> 16) |
         (__builtin_bit_cast(uint, r2b) & HI_MASK);
}

// Async X staging: one 64-row x 64-float tile = 1024 x 16B chunks, staged by
// 8 waves x 2 sweeps via global_load_lds (LDS dest linear: wave-uniform base
// + lane*16). Bank-conflict-free fragment reads come from permuting the
// GLOBAL source chunk within each row: stored chunk s holds original chunk
// s^(r&7); the reader applies the same XOR (involution). Per 16-lane row
// group the fetched chunks are a permutation of the 256B row -> coalesced.
__device__ __forceinline__ void fq_stage(const float* __restrict__ inputs,
        int row0, int m, float* buf, int w, int lane) {
    #pragma unroll
    for (int i = 0; i < 2; ++i) {
        const int blk = i * 8 + w;            // 0..15, wave-uniform
        const int f   = (blk << 6) + lane;    // chunk id 0..1023
        const int r   = f >> 4;               // row 0..63
        const int c   = (f & 15) ^ (r & 7);   // source chunk (swizzled)
        const float* src = inputs + ((size_t)(row0 + r) * MQ + m) * CQ + (c << 2);
        __builtin_amdgcn_global_load_lds(
            (const __attribute__((address_space(1))) void*)src,
            (__attribute__((address_space(3))) void*)(buf + (blk << 8)),
            16, 0, 0);
    }
}

// ---------------------------------------------------------------------------
// Fused kernel. Block = 8 waves; wave (rw=w&3, chh=w>>2) owns 16 rows x 128
// codes per tile: acc = 8 n-tiles of f32x4 = 32 regs, afr = 6 shortx8,
// bfr = 8 shortx8 (same per-wave shape as the measured VGPR=44 round-13).
// LDS: B fragments 96 KB + X dbuf 32 KB + c2/argmin ~2.8 KB = 133 KB.
// ---------------------------------------------------------------------------
__global__ __launch_bounds__(512, 2) void fq_fused_kernel(
        const float* __restrict__ inputs,
        const float* __restrict__ codebook,
        float* __restrict__ out_codes,
        float* __restrict__ out_idx) {
    const int m    = blockIdx.y;
    const int rowB = blockIdx.x * RPB;
    const int w    = (int)threadIdx.x >> 6;
    const int lane = (int)threadIdx.x & 63;
    const int quad = lane >> 4;
    const int col  = lane & 15;
    const int rw   = w & 3;     // row quarter (16 rows) within 64-row tile
    const int chh  = w >> 2;    // code half (128 codes)

    __shared__ unsigned short lds_b[96 * 512];   // 96 KB: 96 frags x 64 lanes x 8
    __shared__ float sx[2][64][64];              // 32 KB: X double buffer
    __shared__ float s_c2v[NQ];
    __shared__ float s_wb[2][64];
    __shared__ int   s_wi[2][64];
    __shared__ int   s_win[64];

    // ---- issue first two X tile stages (async, zero VGPR) ----
    fq_stage(inputs, rowB,      m, &sx[0][0][0], w, lane);
    fq_stage(inputs, rowB + 64, m, &sx[1][0][0], w, lane);

    // ---- transcode this m's codebook slice into LDS fragments + c2 ----
    // item (n, kc): n = item>>3, kc = item&7 (kc == lane&7, so the 8-lane
    // shfl tree below reproduces the old prep kernel's c2 order exactly).
    const float* cbm = codebook + (size_t)m * NQ * CQ;
    #pragma unroll
    for (int it = 0; it < 4; ++it) {
        const int item = (int)threadIdx.x + it * 512;
        const int kc = item & 7;
        const int n  = item >> 3;
        const int nt = n >> 4, cc = n & 15;
        const int h = kc >> 2, q = kc & 3;
        const float* src = cbm + (size_t)n * CQ + kc * 8;
        const float4 va = *(const float4*)src;
        const float4 vb = *(const float4*)(src + 4);
        const float el[8] = {va.x, va.y, va.z, va.w, vb.x, vb.y, vb.z, vb.w};

        float s = 0.0f;
        #pragma unroll
        for (int u = 0; u < 8; ++u) s = fmaf(el[u], el[u], s);
        s += __shfl_xor(s, 1, 64);
        s += __shfl_xor(s, 2, 64);
        s += __shfl_xor(s, 4, 64);
        if (kc == 0) s_c2v[n] = s;

        uint p0[4], p1[4], p2[4];
        #pragma unroll
        for (int u = 0; u < 4; ++u)
            split3_pair(el[2 * u], el[2 * u + 1], p0[u], p1[u], p2[u]);
        const int lf = q * 16 + cc;
        #pragma unroll
        for (int j = 0; j < 3; ++j) {
            const uint* p = (j == 0) ? p0 : (j == 1) ? p1 : p2;
            unsigned short* dst =
                &lds_b[(((j << 1) + h) * 16 + nt) * 512 + lf * 8];
            *(uint4*)dst = make_uint4(p[0], p[1], p[2], p[3]);
        }
    }
    __syncthreads();   // B + c2 ready; X tiles 0,1 drained (vmcnt0 at barrier)

    float c2r[8];
    #pragma unroll
    for (int nt = 0; nt < 8; ++nt)
        c2r[nt] = s_c2v[chh * 128 + nt * 16 + col];

    #pragma unroll 1
    for (int t = 0; t < NTILES; ++t) {
        const int row0 = rowB + t * 64;
        const float* sxb = &sx[t & 1][0][0];

        // ---- A-fragments: 6 (i,h), truncation-split into registers ----
        shortx8 afr[3][2];
        const int r = rw * 16 + col;
        const float* rowp = sxb + r * 64;
        #pragma unroll
        for (int h = 0; h < 2; ++h) {
            const int p0i = (h * 8 + quad * 2) ^ (r & 7);   // swizzled chunk
            const float4 va = *(const float4*)(rowp + (p0i << 2));
            const float4 vb = *(const float4*)(rowp + ((p0i ^ 1) << 2));
            const float el[8] = {va.x, va.y, va.z, va.w, vb.x, vb.y, vb.z, vb.w};
            uint q0[4], q1[4], q2[4];
            #pragma unroll
            for (int u = 0; u < 4; ++u)
                split3_pair(el[2 * u], el[2 * u + 1], q0[u], q1[u], q2[u]);
            afr[0][h] = __builtin_bit_cast(shortx8,
                make_uint4(q0[0], q0[1], q0[2], q0[3]));
            afr[1][h] = __builtin_bit_cast(shortx8,
                make_uint4(q1[0], q1[1], q1[2], q1[3]));
            afr[2][h] = __builtin_bit_cast(shortx8,
                make_uint4(q2[0], q2[1], q2[2], q2[3]));
        }

        f32x4 acc[8];
        #pragma unroll
        for (int nt = 0; nt < 8; ++nt)
            acc[nt] = (f32x4){0.f, 0.f, 0.f, 0.f};

        // ---- hot loop: ds_read_b128 B-fragments + MFMA ----
        #pragma unroll
        for (int h = 0; h < 2; ++h) {
            #pragma unroll
            for (int j = 0; j < 3; ++j) {
                shortx8 bfr[8];
                #pragma unroll
                for (int nt = 0; nt < 8; ++nt)
                    bfr[nt] = *(const shortx8*)
                        &lds_b[(((j << 1) + h) * 16 + chh * 8 + nt) * 512
                               + lane * 8];
                #pragma unroll
                for (int i = 0; i <= 2 - j; ++i) {
                    #pragma unroll
                    for (int nt = 0; nt < 8; ++nt)
                        acc[nt] = __builtin_amdgcn_mfma_f32_16x16x32_bf16(
                            afr[i][h], bfr[nt], acc[nt], 0, 0, 0);
                }
            }
        }

        // ---- epilogue: d = c2 - 2*xc; per-row argmin, lowest n on ties ----
        #pragma unroll
        for (int reg = 0; reg < 4; ++reg) {
            float bd = FLT_MAX; int bi = 0;
            #pragma unroll
            for (int nt = 0; nt < 8; ++nt) {
                const float d = fmaf(-2.0f, acc[nt][reg], c2r[nt]);
                if (d < bd) { bd = d; bi = chh * 128 + nt * 16 + col; }
            }
            #pragma unroll
            for (int mask = 1; mask <= 8; mask <<= 1) {   // over 16 col lanes
                const float od = __shfl_xor(bd, mask, 64);
                const int   oi = __shfl_xor(bi, mask, 64);
                if (od < bd || (od == bd && oi < bi)) { bd = od; bi = oi; }
            }
            if (col == 0) {
                const int rr = rw * 16 + quad * 4 + reg;   // row within 64
                s_wb[chh][rr] = bd;
                s_wi[chh][rr] = bi;
            }
        }
        __syncthreads();   // barrier1: all argmin partials written

        // cross code-half combine (chh=0 holds lower n: ties keep it)
        if (w == 0) {
            float bd = s_wb[0][lane]; int bi = s_wi[0][lane];
            const float od = s_wb[1][lane]; const int oi = s_wi[1][lane];
            if (od < bd || (od == bd && oi < bi)) { bd = od; bi = oi; }
            s_win[lane] = bi;
            out_idx[(size_t)(row0 + lane) * MQ + m] = (float)bi;
        }
        __syncthreads();   // barrier2: s_win visible; sx[t&1] fully consumed

        // issue stage for tile t+2 into the buffer just consumed; its forced
        // vmcnt drain lands at barrier1(t+1) -> hidden under a full tile.
        if (t + 2 < NTILES)
            fq_stage(inputs, row0 + 128, m, &sx[t & 1][0][0], w, lane);

        // gather codes: wave w writes rows w*8..+7, lane = element (256B st)
        #pragma unroll 4
        for (int jj = 0; jj < 8; ++jj) {
            const int rr = w * 8 + jj;
            const int bn = s_win[rr];
            out_codes[((size_t)(row0 + rr) * MQ + m) * CQ + lane] =
                cbm[(size_t)bn * CQ + lane];
        }
    }
}

extern "C" void kernel_launch(void* const* d_in, const int* in_sizes, int n_in,
                              void* d_out, int out_size, void* d_ws, size_t ws_size,
                              hipStream_t stream) {
    const float* inputs   = (const float*)d_in[0];   // [B, M, C]
    const float* codebook = (const float*)d_in[1];   // [M, N, C]
    float* out_codes = (float*)d_out;                        // [B, M, C]
    float* out_idx   = (float*)d_out + (size_t)BQ * MQ * CQ; // [B, M]
    (void)d_ws; (void)ws_size;

    fq_fused_kernel<<<dim3(BQ / RPB, MQ), 512, 0, stream>>>(
        inputs, codebook, out_codes, out_idx);
}

// Round 6
// 108.146 us; speedup vs baseline: 1.1331x; 1.0800x over previous
//
#include <hip/hip_runtime.h>
#include <hip/hip_bf16.h>
#include <float.h>

// FactoredQuantizer: B=8192, M=16, N=256, C=64
// inputs  [B, M, C] fp32;  codebook [M, N, C] fp32
// out = codes [B, M, C] fp32 ++ idx [B, M] (as fp32 values)
//
// Round 15: barrier-free free-running waves. Five structural variants all
// landed at 51+-2 us with no pipe above 26% -> the shared culprit is the
// phase-lockstep block structure (barrier-aligned waves expose every
// dependent-latency chain serially). This round: ONE barrier in the whole
// kernel (after the in-LDS B transcode). Each wave then independently owns
// 32 rows x 256 codes: A read directly from global (per-lane, fully
// consumes 64B lines -> no amplification, no staging, no barrier), B via
// ds_read_b128 from LDS, argmin fully in-wave (two sequential 128-code
// passes reusing acc[8]; cross-pass combine in registers), code gather via
// __shfl broadcast. 16 waves/block, 4 waves/SIMD, free-running -> one
// wave's epilogue overlaps another's MFMAs. Register budget ~120 <= 128
// (__launch_bounds__(1024,4)). MFMA per-chain order, c2 summation order,
// and tie rules identical to the passing kernel -> bit-identical output.

#define BQ 8192
#define MQ 16
#define NQ 256
#define CQ 64
#define RPB 512       // rows per block (16 waves x 32 rows)

typedef short  shortx8 __attribute__((ext_vector_type(8)));
typedef float  f32x4   __attribute__((ext_vector_type(4)));

#define HI_MASK 0xffff0000u

// Truncation 3-split of two floats a,b packed into three dwords
// (low short = a's bf16, high short = b's bf16). Exact: a0+a1+a2 == a.
__device__ __forceinline__ void split3_pair(float a, float b,
                                            uint& q0, uint& q1, uint& q2) {
    const uint ba = __builtin_bit_cast(uint, a);
    const uint bb = __builtin_bit_cast(uint, b);
    q0 = (ba >> 16) | (bb & HI_MASK);
    const float r1a = a - __builtin_bit_cast(float, ba & HI_MASK);
    const float r1b = b - __builtin_bit_cast(float, bb & HI_MASK);
    const uint c1a = __builtin_bit_cast(uint, r1a);
    const uint c1b = __builtin_bit_cast(uint, r1b);
    q1 = (c1a >> 16) | (c1b & HI_MASK);
    const float r2a = r1a - __builtin_bit_cast(float, c1a & HI_MASK);
    const float r2b = r1b - __builtin_bit_cast(float, c1b & HI_MASK);
    q2 = (__builtin_bit_cast(uint, r2a) >> 16) |
         (__builtin_bit_cast(uint, r2b) & HI_MASK);
}

// ---------------------------------------------------------------------------
// Fused kernel. Grid (16,16) = 256 blocks = 1/CU; block = 1024 threads.
// Phase 1 (once): transcode this m's codebook slice into LDS bf16x3
// fragments (96 KB, layout identical to round 14) + c2 (prep's exact
// summation order). ONE __syncthreads. Phase 2: wave w free-runs over rows
// [rowB + w*32, +32) as 2 tiles of 16 rows x 256 codes.
// ---------------------------------------------------------------------------
__global__ __launch_bounds__(1024, 4) void fq_fused_kernel(
        const float* __restrict__ inputs,
        const float* __restrict__ codebook,
        float* __restrict__ out_codes,
        float* __restrict__ out_idx) {
    const int m    = blockIdx.y;
    const int rowB = blockIdx.x * RPB;
    const int w    = (int)threadIdx.x >> 6;
    const int lane = (int)threadIdx.x & 63;
    const int quad = lane >> 4;
    const int col  = lane & 15;

    __shared__ unsigned short lds_b[96 * 512];   // 96 KB: 96 frags x 64 lanes x 8
    __shared__ float s_c2v[NQ];

    // ---- transcode codebook slice into LDS fragments + c2 (once) ----
    // item (n, kc): n = item>>3, kc = item&7 (kc == lane&7 -> the 8-lane
    // shfl tree reproduces the original prep kernel's c2 order exactly).
    const float* cbm = codebook + (size_t)m * NQ * CQ;
    #pragma unroll
    for (int it = 0; it < 2; ++it) {
        const int item = (int)threadIdx.x + it * 1024;
        const int kc = item & 7;
        const int n  = item >> 3;
        const int nt = n >> 4, cc = n & 15;
        const int h = kc >> 2, q = kc & 3;
        const float* src = cbm + (size_t)n * CQ + kc * 8;
        const float4 va = *(const float4*)src;
        const float4 vb = *(const float4*)(src + 4);
        const float el[8] = {va.x, va.y, va.z, va.w, vb.x, vb.y, vb.z, vb.w};

        float s = 0.0f;
        #pragma unroll
        for (int u = 0; u < 8; ++u) s = fmaf(el[u], el[u], s);
        s += __shfl_xor(s, 1, 64);
        s += __shfl_xor(s, 2, 64);
        s += __shfl_xor(s, 4, 64);
        if (kc == 0) s_c2v[n] = s;

        uint p0[4], p1[4], p2[4];
        #pragma unroll
        for (int u = 0; u < 4; ++u)
            split3_pair(el[2 * u], el[2 * u + 1], p0[u], p1[u], p2[u]);
        const int lf = q * 16 + cc;
        #pragma unroll
        for (int j = 0; j < 3; ++j) {
            const uint* p = (j == 0) ? p0 : (j == 1) ? p1 : p2;
            unsigned short* dst =
                &lds_b[(((j << 1) + h) * 16 + nt) * 512 + lf * 8];
            *(uint4*)dst = make_uint4(p[0], p[1], p[2], p[3]);
        }
    }
    __syncthreads();   // the ONLY barrier: B fragments + c2 ready

    // ---- free-running per-wave main loop: 2 tiles of 16 rows x 256 ----
    #pragma unroll 1
    for (int tt = 0; tt < 2; ++tt) {
        const int row0 = rowB + w * 32 + tt * 16;

        // A-fragments: direct per-lane global reads (row = row0+col).
        // Lane (quad,col) reads x[row0+col][h*32+quad*8 .. +8]; the 8 lanes
        // sharing a row jointly consume the full 256B row -> every 64B line
        // fully used, no fetch amplification.
        const float* xb = inputs + ((size_t)(row0 + col) * MQ + m) * CQ;
        shortx8 afr[3][2];
        #pragma unroll
        for (int h = 0; h < 2; ++h) {
            const float4 va = *(const float4*)(xb + h * 32 + quad * 8);
            const float4 vb = *(const float4*)(xb + h * 32 + quad * 8 + 4);
            const float el[8] = {va.x, va.y, va.z, va.w, vb.x, vb.y, vb.z, vb.w};
            uint q0[4], q1[4], q2[4];
            #pragma unroll
            for (int u = 0; u < 4; ++u)
                split3_pair(el[2 * u], el[2 * u + 1], q0[u], q1[u], q2[u]);
            afr[0][h] = __builtin_bit_cast(shortx8,
                make_uint4(q0[0], q0[1], q0[2], q0[3]));
            afr[1][h] = __builtin_bit_cast(shortx8,
                make_uint4(q1[0], q1[1], q1[2], q1[3]));
            afr[2][h] = __builtin_bit_cast(shortx8,
                make_uint4(q2[0], q2[1], q2[2], q2[3]));
        }

        // Two sequential code-half passes reusing acc[8]; carry (bd,bi).
        float bd0[4]; int bi0[4];
        #pragma unroll 1
        for (int chh = 0; chh < 2; ++chh) {
            float c2r[8];
            #pragma unroll
            for (int nt = 0; nt < 8; ++nt)
                c2r[nt] = s_c2v[chh * 128 + nt * 16 + col];

            f32x4 acc[8];
            #pragma unroll
            for (int nt = 0; nt < 8; ++nt)
                acc[nt] = (f32x4){0.f, 0.f, 0.f, 0.f};

            // hot loop: ds_read_b128 B-fragments + MFMA (no barriers)
            #pragma unroll
            for (int h = 0; h < 2; ++h) {
                #pragma unroll
                for (int j = 0; j < 3; ++j) {
                    shortx8 bfr[8];
                    #pragma unroll
                    for (int nt = 0; nt < 8; ++nt)
                        bfr[nt] = *(const shortx8*)
                            &lds_b[(((j << 1) + h) * 16 + chh * 8 + nt) * 512
                                   + lane * 8];
                    #pragma unroll
                    for (int i = 0; i <= 2 - j; ++i) {
                        #pragma unroll
                        for (int nt = 0; nt < 8; ++nt)
                            acc[nt] = __builtin_amdgcn_mfma_f32_16x16x32_bf16(
                                afr[i][h], bfr[nt], acc[nt], 0, 0, 0);
                    }
                }
            }

            // per-pass argmin: d = c2 - 2*xc; lowest n on ties
            #pragma unroll
            for (int reg = 0; reg < 4; ++reg) {
                float bd = FLT_MAX; int bi = 0;
                #pragma unroll
                for (int nt = 0; nt < 8; ++nt) {
                    const float d = fmaf(-2.0f, acc[nt][reg], c2r[nt]);
                    if (d < bd) { bd = d; bi = chh * 128 + nt * 16 + col; }
                }
                #pragma unroll
                for (int mask = 1; mask <= 8; mask <<= 1) { // over 16 col lanes
                    const float od = __shfl_xor(bd, mask, 64);
                    const int   oi = __shfl_xor(bi, mask, 64);
                    if (od < bd || (od == bd && oi < bi)) { bd = od; bi = oi; }
                }
                if (chh == 0) { bd0[reg] = bd; bi0[reg] = bi; }
                else {
                    // cross-half combine (pass 0 holds lower n: ties keep it)
                    if (bd < bd0[reg] || (bd == bd0[reg] && bi < bi0[reg])) {
                        bd0[reg] = bd; bi0[reg] = bi;
                    }
                }
            }
        }

        // idx write: lane (quad, col==0) owns rows quad*4 + reg
        if (col == 0) {
            #pragma unroll
            for (int reg = 0; reg < 4; ++reg)
                out_idx[(size_t)(row0 + quad * 4 + reg) * MQ + m] =
                    (float)bi0[reg];
        }

        // gather codes: row jj's winner lives on lane (jj>>2)*16, reg jj&3
        #pragma unroll
        for (int jj = 0; jj < 16; ++jj) {
            const int bn = __shfl(bi0[jj & 3], (jj >> 2) * 16, 64);
            out_codes[((size_t)(row0 + jj) * MQ + m) * CQ + lane] =
                cbm[(size_t)bn * CQ + lane];
        }
    }
}

extern "C" void kernel_launch(void* const* d_in, const int* in_sizes, int n_in,
                              void* d_out, int out_size, void* d_ws, size_t ws_size,
                              hipStream_t stream) {
    const float* inputs   = (const float*)d_in[0];   // [B, M, C]
    const float* codebook = (const float*)d_in[1];   // [M, N, C]
    float* out_codes = (float*)d_out;                        // [B, M, C]
    float* out_idx   = (float*)d_out + (size_t)BQ * MQ * CQ; // [B, M]
    (void)d_ws; (void)ws_size;

    fq_fused_kernel<<<dim3(BQ / RPB, MQ), 1024, 0, stream>>>(
        inputs, codebook, out_codes, out_idx);
}